// Round 6
// baseline (416.496 us; speedup 1.0000x reference)
//
#include <hip/hip_runtime.h>
#include <float.h>

#define D_IN  128
#define D_OUT 32
#define H     512
#define W4    128            // W/4 float4 lanes per row
#define SEG   16             // output h rows per thread (K1)
#define NSEG  (H / SEG)      // 32 segments
#define ZSTEPS (SEG + 8)     // 24 z-conv rows per segment (1.5x redundancy)
#define SLICE (H * W4)       // f4 per depth slice

// ordered-uint encoding: monotone float -> uint32 for atomicMin/Max
__device__ __forceinline__ unsigned f2key(float f) {
    unsigned u = __float_as_uint(f);
    return (u & 0x80000000u) ? ~u : (u | 0x80000000u);
}
__device__ __forceinline__ float key2f(unsigned k) {
    unsigned u = (k & 0x80000000u) ? (k ^ 0x80000000u) : ~k;
    return __uint_as_float(u);
}

// K1: fused z-conv (stride4,pad3) + h-conv (pad4) via register ring.
// Thread owns (d, segment, c4 column); marches 24 z-rows, emits 16 h-rows.
// Pure streaming: no LDS, no barriers, 9 independent coalesced loads/step.
__global__ __launch_bounds__(256)
void zhconv_kernel(const float* __restrict__ inp, float* __restrict__ out,
                   const float* __restrict__ bxy_p, const float* __restrict__ bz_p) {
    const int t   = blockIdx.x * 256 + threadIdx.x;
    const int c4  = t & (W4 - 1);
    const int ds  = t >> 7;              // (d, seg); uniform per wave
    const int seg = ds & (NSEG - 1);
    const int d   = ds >> 5;             // ds / NSEG
    const int hs  = seg * SEG;

    const float bz = bz_p[0], bx = bxy_p[0];
    const float iz = 1.0f / (2.0f * bz * bz);
    const float ix = 1.0f / (2.0f * bx * bx);
    float wx[9], wzk[9];
    const float4* sp[9];                 // per-tap slice base (clamped), weight zeroed OOB
    const float4* in4 = (const float4*)inp;
#pragma unroll
    for (int k = 0; k < 9; ++k) {
        float dd = (float)(k - 4);
        wx[k] = expf(-dd * dd * ix);
        int din = 4 * d - 3 + k;
        bool ok = (din >= 0) && (din < D_IN);
        int dc = ok ? din : 0;
        wzk[k] = ok ? expf(-dd * dd * iz) : 0.0f;   // branchless d-edge
        sp[k]  = in4 + dc * SLICE + c4;
    }

    float4* out4 = (float4*)out;
    float4 ring[9];
#pragma unroll
    for (int s = 0; s < ZSTEPS; ++s) {
        const int zrow = hs - 4 + s;
        float4 zc = make_float4(0.f, 0.f, 0.f, 0.f);
        if ((unsigned)zrow < H) {        // wave-uniform (seg uniform)
            const int ro = zrow * W4;
#pragma unroll
            for (int k = 0; k < 9; ++k) {
                float4 v = sp[k][ro];
                zc.x += v.x * wzk[k]; zc.y += v.y * wzk[k];
                zc.z += v.z * wzk[k]; zc.w += v.w * wzk[k];
            }
        }
        ring[s % 9] = zc;
        if (s >= 8) {
            const int hout = hs + s - 8;
            float4 acc = make_float4(0.f, 0.f, 0.f, 0.f);
#pragma unroll
            for (int k = 0; k < 9; ++k) {
                float4 v = ring[(s - 8 + k) % 9];
                acc.x += v.x * wx[k]; acc.y += v.y * wx[k];
                acc.z += v.z * wx[k]; acc.w += v.w * wx[k];
            }
            out4[(d * H + hout) * W4 + c4] = acc;
        }
    }
}

// K2: w-conv (pad 4) + fused global min/max (2 atomics per block).
__global__ __launch_bounds__(256)
void wconv_kernel(const float* __restrict__ in, float* __restrict__ out,
                  const float* __restrict__ bxy_p, unsigned* __restrict__ fin_u) {
    const int t   = blockIdx.x * 256 + threadIdx.x;
    const int c4  = t & (W4 - 1);
    const int row = t >> 7;              // d*H + h (0..16383)

    float bx = bxy_p[0];
    float ix = 1.0f / (2.0f * bx * bx);
    float wx[9];
#pragma unroll
    for (int k = 0; k < 9; ++k) {
        float dd = (float)(k - 4);
        wx[k] = expf(-dd * dd * ix);
    }

    const float4* in4 = (const float4*)in;
    const int base = row * W4;
    float4 zv = make_float4(0.f, 0.f, 0.f, 0.f);
    float4 va = (c4 > 0)      ? in4[base + c4 - 1] : zv;
    float4 vb =                 in4[base + c4];
    float4 vc = (c4 < W4 - 1) ? in4[base + c4 + 1] : zv;
    float win[12] = {va.x, va.y, va.z, va.w,
                     vb.x, vb.y, vb.z, vb.w,
                     vc.x, vc.y, vc.z, vc.w};
    float4 o = make_float4(0.f, 0.f, 0.f, 0.f);
#pragma unroll
    for (int k = 0; k < 9; ++k) {
        o.x += win[k]     * wx[k];
        o.y += win[k + 1] * wx[k];
        o.z += win[k + 2] * wx[k];
        o.w += win[k + 3] * wx[k];
    }
    ((float4*)out)[base + c4] = o;

    // block min/max -> 2 atomics (order-independent => deterministic)
    float lmin = fminf(fminf(o.x, o.y), fminf(o.z, o.w));
    float lmax = fmaxf(fmaxf(o.x, o.y), fmaxf(o.z, o.w));
#pragma unroll
    for (int off = 32; off > 0; off >>= 1) {
        lmin = fminf(lmin, __shfl_down(lmin, off, 64));
        lmax = fmaxf(lmax, __shfl_down(lmax, off, 64));
    }
    __shared__ float smin[4], smax[4];
    int lane = threadIdx.x & 63, wv = threadIdx.x >> 6;
    if (lane == 0) { smin[wv] = lmin; smax[wv] = lmax; }
    __syncthreads();
    if (threadIdx.x == 0) {
        float mn = fminf(fminf(smin[0], smin[1]), fminf(smin[2], smin[3]));
        float mx = fmaxf(fmaxf(smax[0], smax[1]), fmaxf(smax[2], smax[3]));
        atomicMin(&fin_u[0], f2key(mn));
        atomicMax(&fin_u[1], f2key(mx));
    }
}

// K3: normalize.
__global__ void norm_kernel(const float* __restrict__ in, float* __restrict__ out,
                            const unsigned* __restrict__ fin_u) {
    int tid = blockIdx.x * blockDim.x + threadIdx.x;
    float mn  = key2f(fin_u[0]);
    float inv = 1.0f / (key2f(fin_u[1]) - mn);
    float4 v = ((const float4*)in)[tid];
    ((float4*)out)[tid] = make_float4((v.x - mn) * inv, (v.y - mn) * inv,
                                      (v.z - mn) * inv, (v.w - mn) * inv);
}

extern "C" void kernel_launch(void* const* d_in, const int* in_sizes, int n_in,
                              void* d_out, int out_size, void* d_ws, size_t ws_size,
                              hipStream_t stream) {
    const float* inp    = (const float*)d_in[0];
    // mu_z / sig_z produce a positive global scale that cancels in min-max norm.
    const float* bet_xy = (const float*)d_in[3];
    const float* bet_z  = (const float*)d_in[4];
    float* out = (float*)d_out;

    char* ws = (char*)d_ws;
    unsigned* fin_u = (unsigned*)ws;                         // [0]=min key [1]=max key
    float* bufA = (float*)(ws + 65536);                      // 32 MiB zh-conv out
    float* bufB = (float*)(ws + 65536 + (size_t)33554432);   // 32 MiB w-conv out

    // init atomic slots: min key = 0xFFFFFFFF, max key = 0x00000000
    hipMemsetAsync(&fin_u[0], 0xFF, 4, stream);
    hipMemsetAsync(&fin_u[1], 0x00, 4, stream);

    // K1: z+h conv, register-ring streaming. 32 d * 32 seg * 128 c4 threads.
    const int K1_THREADS = D_OUT * NSEG * W4;    // 131072
    zhconv_kernel<<<K1_THREADS / 256, 256, 0, stream>>>(inp, bufA, bet_xy, bet_z);

    // K2: w-conv + min/max
    const int NTASK = D_OUT * H * W4;            // 2,097,152 float4
    wconv_kernel<<<NTASK / 256, 256, 0, stream>>>(bufA, bufB, bet_xy, fin_u);

    // K3: normalize
    norm_kernel<<<NTASK / 256, 256, 0, stream>>>(bufB, out, fin_u);
}